// Round 3
// baseline (510.222 us; speedup 1.0000x reference)
//
#include <hip/hip_runtime.h>
#include <hip/hip_bf16.h>

#define B_ 8
#define L_ 256
#define D_ 128
#define H_ 4
#define HD_ 32
#define NB_ 2
#define ROWS (B_*L_)            // 2048
#define NEGV (-4294967295.0f)   // -(2^32)+1 as float

typedef __hip_bfloat16 bf16;

__device__ __forceinline__ float b2f(bf16 x) { return __bfloat162float(x); }
__device__ __forceinline__ float us2f(unsigned short u) {
    return __uint_as_float(((unsigned)u) << 16);
}

// seqs[r,d] = item_emb[log_seqs[r], d] * sqrt(D), zeroed on padding id 0
__global__ void k_embed(const float* __restrict__ item_emb,
                        const int* __restrict__ log_seqs,
                        float* __restrict__ seqs) {
    int idx = blockIdx.x * 256 + threadIdx.x;   // ROWS*D = 262144
    int r = idx >> 7, d = idx & 127;
    int id = log_seqs[r];
    float v = item_emb[id * D_ + d] * 11.3137085f;
    seqs[idx] = (id == 0) ? 0.0f : v;
}

// LayerNorm over D=128; one wave per row, 4 rows per block. X may alias Y.
__global__ void k_ln(const float* X, float* Y,
                     const float* __restrict__ g, const float* __restrict__ b) {
    int wave = threadIdx.x >> 6, lane = threadIdx.x & 63;
    int row = blockIdx.x * 4 + wave;
    const float* x = X + row * D_;
    float x0 = x[lane], x1 = x[lane + 64];
    float s = x0 + x1;
    for (int o = 32; o; o >>= 1) s += __shfl_xor(s, o, 64);
    float m = s * (1.0f / 128.0f);
    float d0 = x0 - m, d1 = x1 - m;
    float v = d0 * d0 + d1 * d1;
    for (int o = 32; o; o >>= 1) v += __shfl_xor(v, o, 64);
    float rstd = rsqrtf(v * (1.0f / 128.0f) + 1e-8f);
    float* y = Y + row * D_;
    y[lane]      = d0 * rstd * g[lane]      + b[lane];
    y[lane + 64] = d1 * rstd * g[lane + 64] + b[lane + 64];
}

__device__ __forceinline__ void storev(float* p, float v) { *p = v; }
__device__ __forceinline__ void storev(bf16* p, float v) { *p = __float2bfloat16(v); }

// C[r,c] = act(sum_k A[r,k]*W[k,c] + bias[c]) [+ resid] [* !pad]
// 8 rows per block; W (fp32 global) staged to LDS as bf16 (rel err ~0.2%,
// threshold is 2% of max|ref| so this is safely inside budget).
template <typename OUT>
__global__ __launch_bounds__(256) void k_gemm(
        const float* __restrict__ A, const float* __restrict__ W,
        const float* __restrict__ bias, const float* resid, OUT* C,
        const int* __restrict__ maskids, int relu) {
    __shared__ float sA[8 * D_];
    __shared__ unsigned short sW[D_ * D_];
    int tid = threadIdx.x;
    int r0 = blockIdx.x * 8;
    #pragma unroll
    for (int i = 0; i < 4; i++) sA[tid + i * 256] = A[r0 * D_ + tid + i * 256];
    #pragma unroll
    for (int i = 0; i < 64; i++) {
        bf16 w = __float2bfloat16(W[tid + i * 256]);
        sW[tid + i * 256] = *(unsigned short*)&w;
    }
    __syncthreads();
    int c = tid & 127, rg = tid >> 7;   // rg selects rows rg*4 .. rg*4+3
    float acc0 = 0, acc1 = 0, acc2 = 0, acc3 = 0;
    #pragma unroll 4
    for (int k = 0; k < D_; k++) {
        float w = us2f(sW[k * D_ + c]);
        acc0 += sA[(rg * 4 + 0) * D_ + k] * w;
        acc1 += sA[(rg * 4 + 1) * D_ + k] * w;
        acc2 += sA[(rg * 4 + 2) * D_ + k] * w;
        acc3 += sA[(rg * 4 + 3) * D_ + k] * w;
    }
    float bv = bias[c];
    float accs[4] = {acc0, acc1, acc2, acc3};
    #pragma unroll
    for (int rr = 0; rr < 4; rr++) {
        int row = r0 + rg * 4 + rr;
        float v = accs[rr] + bv;
        if (relu) v = fmaxf(v, 0.0f);
        if (resid) v += resid[row * D_ + c];
        if (maskids && maskids[row] == 0) v = 0.0f;
        storev(&C[row * D_ + c], v);
    }
}

// One block per (b,q). scores -> softmax -> out (+q_in residual fused).
// Q,K,V are bf16 workspace tensors; pos/time embeddings fp32 inputs.
__global__ __launch_bounds__(256) void k_attn(
        const bf16* __restrict__ Q, const bf16* __restrict__ K,
        const bf16* __restrict__ V, const float* __restrict__ qin,
        const int* __restrict__ log_seqs, const int* __restrict__ tmat,
        const float* __restrict__ posK, const float* __restrict__ posV,
        const float* __restrict__ timeK, const float* __restrict__ timeV,
        float* __restrict__ out) {
    __shared__ float sQ[D_];
    __shared__ float sS[H_][L_];
    __shared__ int   sTM[L_];
    __shared__ float sP[256];
    int tid = threadIdx.x;
    int bq = blockIdx.x;            // b*L + q
    int q  = bq & (L_ - 1);
    int b0 = bq & ~(L_ - 1);        // b*L
    if (tid < D_) sQ[tid] = b2f(Q[bq * D_ + tid]);
    int k = tid;
    int tm = tmat[bq * L_ + k];
    sTM[k] = tm;
    bool padq = (log_seqs[bq] == 0);
    __syncthreads();

    // phase 1: scores[h][k] = Q . (K[k] + posK[k] + timeK[tm]) / sqrt(HD), masked
    const bf16* Krow = K + (b0 + k) * D_;
    #pragma unroll
    for (int h = 0; h < H_; h++) {
        float s = 0.0f;
        int base = h * HD_;
        #pragma unroll
        for (int j = 0; j < HD_; j++) {
            int d = base + j;
            float kv = b2f(Krow[d]) + posK[k * D_ + d] + timeK[tm * D_ + d];
            s += sQ[d] * kv;
        }
        s *= 0.17677669529663687f;  // 1/sqrt(32)
        if (padq || k > q) s = NEGV;
        sS[h][k] = s;
    }
    __syncthreads();

    // phase 2: softmax per head; wave w owns head w
    {
        int h = tid >> 6, lane = tid & 63;
        float v0 = sS[h][lane], v1 = sS[h][lane + 64];
        float v2 = sS[h][lane + 128], v3 = sS[h][lane + 192];
        float m = fmaxf(fmaxf(v0, v1), fmaxf(v2, v3));
        for (int o = 32; o; o >>= 1) m = fmaxf(m, __shfl_xor(m, o, 64));
        float e0 = __expf(v0 - m), e1 = __expf(v1 - m);
        float e2 = __expf(v2 - m), e3 = __expf(v3 - m);
        float ssum = e0 + e1 + e2 + e3;
        for (int o = 32; o; o >>= 1) ssum += __shfl_xor(ssum, o, 64);
        float inv = 1.0f / ssum;
        sS[h][lane] = e0 * inv;       sS[h][lane + 64]  = e1 * inv;
        sS[h][lane + 128] = e2 * inv; sS[h][lane + 192] = e3 * inv;
    }
    __syncthreads();

    // phase 3: out[d] = sum_k A[h(d)][k] * (V[k,d] + posV[k,d] + timeV[tm_k,d])
    int d = tid & 127, half = tid >> 7;
    int h = d >> 5;
    float acc = 0.0f;
    for (int kk = 0; kk < 128; kk++) {
        int kx = half * 128 + kk;
        float a = sS[h][kx];
        int tmk = sTM[kx];
        acc += a * (b2f(V[(b0 + kx) * D_ + d]) + posV[kx * D_ + d]
                    + timeV[tmk * D_ + d]);
    }
    sP[tid] = acc;
    __syncthreads();
    if (tid < 128) {
        out[bq * D_ + tid] = sP[tid] + sP[tid + 128] + qin[bq * D_ + tid];
    }
}

// logits: one wave per output element; pos first 2048, then neg 2048.
__global__ void k_logits(const float* __restrict__ feats,
                         const int* __restrict__ pos_seqs,
                         const int* __restrict__ neg_seqs,
                         const float* __restrict__ item_emb,
                         float* __restrict__ outp) {
    int w = threadIdx.x >> 6, lane = threadIdx.x & 63;
    int o = blockIdx.x * 4 + w;     // 0..4095
    int r = o & (ROWS - 1);
    int id = (o < ROWS) ? pos_seqs[r] : neg_seqs[r];
    const float* f = feats + r * D_;
    float s = f[lane] * item_emb[id * D_ + lane]
            + f[lane + 64] * item_emb[id * D_ + lane + 64];
    for (int oo = 32; oo; oo >>= 1) s += __shfl_xor(s, oo, 64);
    if (lane == 0) outp[o] = s;
}

extern "C" void kernel_launch(void* const* d_in, const int* in_sizes, int n_in,
                              void* d_out, int out_size, void* d_ws, size_t ws_size,
                              hipStream_t stream) {
    const int* log_seqs = (const int*)d_in[1];
    const int* tmat     = (const int*)d_in[2];
    const int* pos_seqs = (const int*)d_in[3];
    const int* neg_seqs = (const int*)d_in[4];
    const float* item_emb = (const float*)d_in[5];
    const float* posK  = (const float*)d_in[6];
    const float* posV  = (const float*)d_in[7];
    const float* timeK = (const float*)d_in[8];
    const float* timeV = (const float*)d_in[9];
    const float* ln1_g = (const float*)d_in[10];
    const float* ln1_b = (const float*)d_in[11];
    const float* Wq = (const float*)d_in[12];
    const float* bqv = (const float*)d_in[13];
    const float* Wk = (const float*)d_in[14];
    const float* bk = (const float*)d_in[15];
    const float* Wv = (const float*)d_in[16];
    const float* bv = (const float*)d_in[17];
    const float* ln2_g = (const float*)d_in[18];
    const float* ln2_b = (const float*)d_in[19];
    const float* W1 = (const float*)d_in[20];
    const float* b1 = (const float*)d_in[21];
    const float* W2 = (const float*)d_in[22];
    const float* b2 = (const float*)d_in[23];
    const float* lnf_g = (const float*)d_in[24];
    const float* lnf_b = (const float*)d_in[25];

    // Workspace layout (3.5 MB total):
    //   [0, 1MB)     s_seqs  fp32 [2048,128]
    //   [1MB, 2MB)   s_qin   fp32 [2048,128]
    //   [2MB, 2.5MB) s_Q     bf16 [2048,128]
    //   [2.5, 3MB)   s_K     bf16
    //   [3, 3.5MB)   s_V     bf16
    //   [2MB, 3MB)   s_h / s_f fp32 — overlays Q,K (dead during FFN / epilogue)
    const int NE = ROWS * D_;       // 262144
    char* wsb = (char*)d_ws;
    float* s_seqs = (float*)(wsb + 0);
    float* s_qin  = (float*)(wsb + (size_t)NE * 4);
    bf16*  s_Q    = (bf16*) (wsb + (size_t)NE * 8);
    bf16*  s_K    = (bf16*) (wsb + (size_t)NE * 8 + (size_t)NE * 2);
    bf16*  s_V    = (bf16*) (wsb + (size_t)NE * 8 + (size_t)NE * 4);
    float* s_h    = (float*)(wsb + (size_t)NE * 8);   // overlays Q,K
    float* s_f    = (float*)(wsb + (size_t)NE * 8);   // overlays Q,K

    k_embed<<<1024, 256, 0, stream>>>(item_emb, log_seqs, s_seqs);
    for (int i = 0; i < NB_; i++) {
        k_ln<<<512, 256, 0, stream>>>(s_seqs, s_qin, ln1_g + i * D_, ln1_b + i * D_);
        k_gemm<bf16><<<256, 256, 0, stream>>>(s_qin,  Wq + i * D_ * D_, bqv + i * D_, nullptr, s_Q, nullptr, 0);
        k_gemm<bf16><<<256, 256, 0, stream>>>(s_seqs, Wk + i * D_ * D_, bk + i * D_, nullptr, s_K, nullptr, 0);
        k_gemm<bf16><<<256, 256, 0, stream>>>(s_seqs, Wv + i * D_ * D_, bv + i * D_, nullptr, s_V, nullptr, 0);
        k_attn<<<2048, 256, 0, stream>>>(s_Q, s_K, s_V, s_qin, log_seqs, tmat,
                                         posK, posV, timeK, timeV, s_seqs);
        k_ln<<<512, 256, 0, stream>>>(s_seqs, s_seqs, ln2_g + i * D_, ln2_b + i * D_);
        k_gemm<float><<<256, 256, 0, stream>>>(s_seqs, W1 + i * D_ * D_, b1 + i * D_, nullptr, s_h, nullptr, 1);
        k_gemm<float><<<256, 256, 0, stream>>>(s_h,   W2 + i * D_ * D_, b2 + i * D_, s_seqs, s_seqs, log_seqs, 0);
    }
    k_ln<<<512, 256, 0, stream>>>(s_seqs, s_f, lnf_g, lnf_b);
    k_logits<<<1024, 256, 0, stream>>>(s_f, pos_seqs, neg_seqs, item_emb, (float*)d_out);
}

// Round 4
// 305.344 us; speedup vs baseline: 1.6710x; 1.6710x over previous
//
#include <hip/hip_runtime.h>
#include <hip/hip_bf16.h>

#define B_ 8
#define L_ 256
#define D_ 128
#define H_ 4
#define HD_ 32
#define NB_ 2
#define ROWS (B_*L_)            // 2048
#define NEGV (-4294967295.0f)   // -(2^32)+1 as float

typedef __hip_bfloat16 bf16;

__device__ __forceinline__ float b2f(bf16 x) { return __bfloat162float(x); }
__device__ __forceinline__ float us2f(unsigned short u) {
    return __uint_as_float(((unsigned)u) << 16);
}

// seqs[r,d] = item_emb[log_seqs[r], d] * sqrt(D), zeroed on padding id 0
__global__ void k_embed(const float* __restrict__ item_emb,
                        const int* __restrict__ log_seqs,
                        float* __restrict__ seqs) {
    int idx = blockIdx.x * 256 + threadIdx.x;   // ROWS*D = 262144
    int r = idx >> 7, d = idx & 127;
    int id = log_seqs[r];
    float v = item_emb[id * D_ + d] * 11.3137085f;
    seqs[idx] = (id == 0) ? 0.0f : v;
}

// LayerNorm over D=128; one wave per row, 4 rows per block. X may alias Y.
__global__ void k_ln(const float* X, float* Y,
                     const float* __restrict__ g, const float* __restrict__ b) {
    int wave = threadIdx.x >> 6, lane = threadIdx.x & 63;
    int row = blockIdx.x * 4 + wave;
    const float* x = X + row * D_;
    float x0 = x[lane], x1 = x[lane + 64];
    float s = x0 + x1;
    for (int o = 32; o; o >>= 1) s += __shfl_xor(s, o, 64);
    float m = s * (1.0f / 128.0f);
    float d0 = x0 - m, d1 = x1 - m;
    float v = d0 * d0 + d1 * d1;
    for (int o = 32; o; o >>= 1) v += __shfl_xor(v, o, 64);
    float rstd = rsqrtf(v * (1.0f / 128.0f) + 1e-8f);
    float* y = Y + row * D_;
    y[lane]      = d0 * rstd * g[lane]      + b[lane];
    y[lane + 64] = d1 * rstd * g[lane + 64] + b[lane + 64];
}

__device__ __forceinline__ void storev(float* p, float v) { *p = v; }
__device__ __forceinline__ void storev(bf16* p, float v) { *p = __float2bfloat16(v); }

// C[r,c] = act(sum_k A[r,k]*W[k,c] + bias[c]) [+ posadd[r%L,c]] [+ resid] [* !pad]
// 8 rows per block; W (fp32 global) staged to LDS as bf16.
template <typename OUT>
__global__ __launch_bounds__(256) void k_gemm(
        const float* __restrict__ A, const float* __restrict__ W,
        const float* __restrict__ bias, const float* resid, OUT* C,
        const int* __restrict__ maskids, int relu,
        const float* __restrict__ posadd) {
    __shared__ float sA[8 * D_];
    __shared__ unsigned short sW[D_ * D_];
    int tid = threadIdx.x;
    int r0 = blockIdx.x * 8;
    #pragma unroll
    for (int i = 0; i < 4; i++) sA[tid + i * 256] = A[r0 * D_ + tid + i * 256];
    #pragma unroll
    for (int i = 0; i < 64; i++) {
        bf16 w = __float2bfloat16(W[tid + i * 256]);
        sW[tid + i * 256] = *(unsigned short*)&w;
    }
    __syncthreads();
    int c = tid & 127, rg = tid >> 7;   // rg selects rows rg*4 .. rg*4+3
    float acc0 = 0, acc1 = 0, acc2 = 0, acc3 = 0;
    #pragma unroll 4
    for (int k = 0; k < D_; k++) {
        float w = us2f(sW[k * D_ + c]);
        acc0 += sA[(rg * 4 + 0) * D_ + k] * w;
        acc1 += sA[(rg * 4 + 1) * D_ + k] * w;
        acc2 += sA[(rg * 4 + 2) * D_ + k] * w;
        acc3 += sA[(rg * 4 + 3) * D_ + k] * w;
    }
    float bv = bias[c];
    float accs[4] = {acc0, acc1, acc2, acc3};
    #pragma unroll
    for (int rr = 0; rr < 4; rr++) {
        int row = r0 + rg * 4 + rr;
        float v = accs[rr] + bv;
        if (relu) v = fmaxf(v, 0.0f);
        if (posadd) v += posadd[(row & (L_ - 1)) * D_ + c];
        if (resid) v += resid[row * D_ + c];
        if (maskids && maskids[row] == 0) v = 0.0f;
        storev(&C[row * D_ + c], v);
    }
}

// One block per (b,q). scores -> softmax -> out (+q_in residual fused).
// K,V workspace already include posK/posV. Q,K,V bf16.
__global__ __launch_bounds__(256) void k_attn(
        const bf16* __restrict__ Q, const bf16* __restrict__ Kb,
        const bf16* __restrict__ Vb, const float* __restrict__ qin,
        const int* __restrict__ log_seqs, const int* __restrict__ tmat,
        const float* __restrict__ timeK, const float* __restrict__ timeV,
        float* __restrict__ out) {
    __shared__ __align__(16) float sQ[D_];
    __shared__ float sS[H_][L_];
    __shared__ int   sTM[L_];
    __shared__ float sPr[8][D_];
    int tid = threadIdx.x;
    int bq = blockIdx.x;            // b*L + q
    int q  = bq & (L_ - 1);
    int b0 = bq & ~(L_ - 1);        // b*L
    if (tid < D_) sQ[tid] = b2f(Q[bq * D_ + tid]);
    int k = tid;
    int tm = tmat[bq * L_ + k];
    sTM[k] = tm;
    bool padq = (log_seqs[bq] == 0);
    __syncthreads();

    // phase 1: scores[h][k] = Q . (K'[k] + timeK[tm]) / sqrt(HD); vectorized.
    {
        float acc[4] = {0.f, 0.f, 0.f, 0.f};
        bool active = (k <= q) && !padq;
        if (active) {
            const uint4*  K4 = (const uint4*) (Kb + (size_t)(b0 + k) * D_);
            const float4* T4 = (const float4*)(timeK + (size_t)tm * D_);
            const float4* Q4 = (const float4*)sQ;
            #pragma unroll
            for (int c = 0; c < 16; c++) {     // 8 dims per chunk; head = c>>2
                uint4 kv = K4[c];
                float4 ta = T4[2 * c], tb = T4[2 * c + 1];
                float4 qa = Q4[2 * c], qb = Q4[2 * c + 1];
                const unsigned short* ku = (const unsigned short*)&kv;
                float p = qa.x * (us2f(ku[0]) + ta.x)
                        + qa.y * (us2f(ku[1]) + ta.y)
                        + qa.z * (us2f(ku[2]) + ta.z)
                        + qa.w * (us2f(ku[3]) + ta.w)
                        + qb.x * (us2f(ku[4]) + tb.x)
                        + qb.y * (us2f(ku[5]) + tb.y)
                        + qb.z * (us2f(ku[6]) + tb.z)
                        + qb.w * (us2f(ku[7]) + tb.w);
                acc[c >> 2] += p;
            }
        }
        const float scale = 0.17677669529663687f;  // 1/sqrt(32)
        #pragma unroll
        for (int h = 0; h < H_; h++)
            sS[h][k] = active ? acc[h] * scale : NEGV;
    }
    __syncthreads();

    // phase 2: softmax per head; wave w owns head w
    {
        int h = tid >> 6, lane = tid & 63;
        float v0 = sS[h][lane], v1 = sS[h][lane + 64];
        float v2 = sS[h][lane + 128], v3 = sS[h][lane + 192];
        float m = fmaxf(fmaxf(v0, v1), fmaxf(v2, v3));
        for (int o = 32; o; o >>= 1) m = fmaxf(m, __shfl_xor(m, o, 64));
        float e0 = __expf(v0 - m), e1 = __expf(v1 - m);
        float e2 = __expf(v2 - m), e3 = __expf(v3 - m);
        float ssum = e0 + e1 + e2 + e3;
        for (int o = 32; o; o >>= 1) ssum += __shfl_xor(ssum, o, 64);
        float inv = 1.0f / ssum;
        sS[h][lane] = e0 * inv;       sS[h][lane + 64]  = e1 * inv;
        sS[h][lane + 128] = e2 * inv; sS[h][lane + 192] = e3 * inv;
    }
    __syncthreads();

    // phase 3: out[d] = sum_k A[h(d)][k] * (V'[k,d] + timeV[tm_k,d])
    // thread = (d-group of 4, k-slice of 32); vector loads; causal clamp.
    {
        int dq = tid & 31;          // dims dq*4 .. dq*4+3
        int slice = tid >> 5;       // k in [slice*32, slice*32+32)
        int h = dq >> 3;
        int kend = padq ? L_ : (q + 1);
        int k0 = slice * 32;
        int kmax = kend - k0; kmax = kmax < 0 ? 0 : (kmax > 32 ? 32 : kmax);
        float a0 = 0, a1 = 0, a2 = 0, a3 = 0;
        for (int kk = 0; kk < kmax; kk++) {
            int kx = k0 + kk;
            float a = sS[h][kx];
            int tmk = sTM[kx];
            ushort4 v4 = ((const ushort4*)(Vb + (size_t)(b0 + kx) * D_))[dq];
            float4  t4 = ((const float4*)(timeV + (size_t)tmk * D_))[dq];
            a0 += a * (us2f(v4.x) + t4.x);
            a1 += a * (us2f(v4.y) + t4.y);
            a2 += a * (us2f(v4.z) + t4.z);
            a3 += a * (us2f(v4.w) + t4.w);
        }
        sPr[slice][dq * 4 + 0] = a0;
        sPr[slice][dq * 4 + 1] = a1;
        sPr[slice][dq * 4 + 2] = a2;
        sPr[slice][dq * 4 + 3] = a3;
    }
    __syncthreads();
    if (tid < D_) {
        float s = 0;
        #pragma unroll
        for (int sl = 0; sl < 8; sl++) s += sPr[sl][tid];
        out[bq * D_ + tid] = s + qin[bq * D_ + tid];
    }
}

// logits: one wave per output element; pos first 2048, then neg 2048.
__global__ void k_logits(const float* __restrict__ feats,
                         const int* __restrict__ pos_seqs,
                         const int* __restrict__ neg_seqs,
                         const float* __restrict__ item_emb,
                         float* __restrict__ outp) {
    int w = threadIdx.x >> 6, lane = threadIdx.x & 63;
    int o = blockIdx.x * 4 + w;     // 0..4095
    int r = o & (ROWS - 1);
    int id = (o < ROWS) ? pos_seqs[r] : neg_seqs[r];
    const float* f = feats + r * D_;
    float s = f[lane] * item_emb[id * D_ + lane]
            + f[lane + 64] * item_emb[id * D_ + lane + 64];
    for (int oo = 32; oo; oo >>= 1) s += __shfl_xor(s, oo, 64);
    if (lane == 0) outp[o] = s;
}

extern "C" void kernel_launch(void* const* d_in, const int* in_sizes, int n_in,
                              void* d_out, int out_size, void* d_ws, size_t ws_size,
                              hipStream_t stream) {
    const int* log_seqs = (const int*)d_in[1];
    const int* tmat     = (const int*)d_in[2];
    const int* pos_seqs = (const int*)d_in[3];
    const int* neg_seqs = (const int*)d_in[4];
    const float* item_emb = (const float*)d_in[5];
    const float* posK  = (const float*)d_in[6];
    const float* posV  = (const float*)d_in[7];
    const float* timeK = (const float*)d_in[8];
    const float* timeV = (const float*)d_in[9];
    const float* ln1_g = (const float*)d_in[10];
    const float* ln1_b = (const float*)d_in[11];
    const float* Wq = (const float*)d_in[12];
    const float* bqv = (const float*)d_in[13];
    const float* Wk = (const float*)d_in[14];
    const float* bk = (const float*)d_in[15];
    const float* Wv = (const float*)d_in[16];
    const float* bv = (const float*)d_in[17];
    const float* ln2_g = (const float*)d_in[18];
    const float* ln2_b = (const float*)d_in[19];
    const float* W1 = (const float*)d_in[20];
    const float* b1 = (const float*)d_in[21];
    const float* W2 = (const float*)d_in[22];
    const float* b2 = (const float*)d_in[23];
    const float* lnf_g = (const float*)d_in[24];
    const float* lnf_b = (const float*)d_in[25];

    // Workspace layout (3.5 MB):
    //   [0, 1MB)     s_seqs fp32   [1MB, 2MB) s_qin fp32
    //   [2, 2.5MB)   s_Q bf16      [2.5, 3MB) s_K bf16 (incl. posK)
    //   [3, 3.5MB)   s_V bf16 (incl. posV)
    //   [2, 3MB)     s_h / s_f fp32 overlays Q,K (dead during FFN / epilogue)
    const int NE = ROWS * D_;       // 262144
    char* wsb = (char*)d_ws;
    float* s_seqs = (float*)(wsb + 0);
    float* s_qin  = (float*)(wsb + (size_t)NE * 4);
    bf16*  s_Q    = (bf16*) (wsb + (size_t)NE * 8);
    bf16*  s_K    = (bf16*) (wsb + (size_t)NE * 8 + (size_t)NE * 2);
    bf16*  s_V    = (bf16*) (wsb + (size_t)NE * 8 + (size_t)NE * 4);
    float* s_h    = (float*)(wsb + (size_t)NE * 8);   // overlays Q,K
    float* s_f    = (float*)(wsb + (size_t)NE * 8);   // overlays Q,K

    k_embed<<<1024, 256, 0, stream>>>(item_emb, log_seqs, s_seqs);
    for (int i = 0; i < NB_; i++) {
        k_ln<<<512, 256, 0, stream>>>(s_seqs, s_qin, ln1_g + i * D_, ln1_b + i * D_);
        k_gemm<bf16><<<256, 256, 0, stream>>>(s_qin,  Wq + i * D_ * D_, bqv + i * D_, nullptr, s_Q, nullptr, 0, nullptr);
        k_gemm<bf16><<<256, 256, 0, stream>>>(s_seqs, Wk + i * D_ * D_, bk + i * D_, nullptr, s_K, nullptr, 0, posK);
        k_gemm<bf16><<<256, 256, 0, stream>>>(s_seqs, Wv + i * D_ * D_, bv + i * D_, nullptr, s_V, nullptr, 0, posV);
        k_attn<<<2048, 256, 0, stream>>>(s_Q, s_K, s_V, s_qin, log_seqs, tmat,
                                         timeK, timeV, s_seqs);
        k_ln<<<512, 256, 0, stream>>>(s_seqs, s_seqs, ln2_g + i * D_, ln2_b + i * D_);
        k_gemm<float><<<256, 256, 0, stream>>>(s_seqs, W1 + i * D_ * D_, b1 + i * D_, nullptr, s_h, nullptr, 1, nullptr);
        k_gemm<float><<<256, 256, 0, stream>>>(s_h,   W2 + i * D_ * D_, b2 + i * D_, s_seqs, s_seqs, log_seqs, 0, nullptr);
    }
    k_ln<<<512, 256, 0, stream>>>(s_seqs, s_f, lnf_g, lnf_b);
    k_logits<<<1024, 256, 0, stream>>>(s_f, pos_seqs, neg_seqs, item_emb, (float*)d_out);
}

// Round 5
// 242.733 us; speedup vs baseline: 2.1020x; 1.2579x over previous
//
#include <hip/hip_runtime.h>
#include <hip/hip_bf16.h>

#define B_ 8
#define L_ 256
#define D_ 128
#define H_ 4
#define NB_ 2
#define ROWS (B_*L_)            // 2048
#define NEGV (-4294967295.0f)   // -(2^32)+1 as float

typedef __hip_bfloat16 bf16;

__device__ __forceinline__ float us2f(unsigned short u){ return __uint_as_float(((unsigned)u)<<16); }
__device__ __forceinline__ unsigned short f2us(float f){ bf16 h=__float2bfloat16(f); return *(unsigned short*)&h; }
__device__ __forceinline__ float b2f(bf16 x){ return __bfloat162float(x); }

struct WPtrs { const float* p[10]; };   // Wq0,Wk0,Wv0,W1_0,W2_0, Wq1,Wk1,Wv1,W1_1,W2_1

// ---- fused: embed (blocks 0..255) + weight fp32->bf16 conversion (blocks 256..415)
__global__ __launch_bounds__(256) void k_prep(const float* __restrict__ item_emb,
        const int* __restrict__ log_seqs, float* __restrict__ seqs,
        WPtrs wp, unsigned short* __restrict__ wsW) {
    int tid = threadIdx.x, bid = blockIdx.x;
    if (bid < 256) {
        int gi = bid*256 + tid;          // float4 index, 65536 total
        int r = gi >> 5, c4 = gi & 31;
        int id = log_seqs[r];
        float4 v = ((const float4*)item_emb)[id*32 + c4];
        float sc = (id==0) ? 0.0f : 11.3137085f;   // sqrt(128)
        v.x*=sc; v.y*=sc; v.z*=sc; v.w*=sc;
        ((float4*)seqs)[gi] = v;
    } else {
        int m = (bid-256) >> 4, ch = (bid-256) & 15;
        float4 v = ((const float4*)wp.p[m])[ch*256 + tid];
        ushort4 o; o.x=f2us(v.x); o.y=f2us(v.y); o.z=f2us(v.z); o.w=f2us(v.w);
        ((ushort4*)(wsW + (size_t)m*16384))[ch*256 + tid] = o;
    }
}

// stage one 128x128 bf16 matrix (32KB) from global to LDS: 8 x uint4 per thread
__device__ __forceinline__ void stage_w(const unsigned short* __restrict__ Wg,
                                        unsigned short* sW, int tid){
    const uint4* src = (const uint4*)Wg;
    uint4* dst = (uint4*)sW;
    #pragma unroll
    for (int j=0;j<8;j++) dst[j*256+tid] = src[j*256+tid];
}

// LayerNorm of 8 rows resident in LDS; thread t: row t>>5, lanes-of-32 x 4 elems.
__device__ __forceinline__ void ln_rows(const float* sA, float* sOut,
        const float* __restrict__ g, const float* __restrict__ b,
        float* qin_out, int r0, int tid){
    int r = tid>>5, l = tid&31;
    const float* x = sA + r*128;
    float x0=x[l], x1=x[l+32], x2=x[l+64], x3=x[l+96];
    float s = x0+x1+x2+x3;
    #pragma unroll
    for (int o=16;o;o>>=1) s += __shfl_xor(s,o,64);   // stays within 32-lane group
    float m = s*(1.f/128.f);
    float d0=x0-m,d1=x1-m,d2=x2-m,d3=x3-m;
    float v = d0*d0+d1*d1+d2*d2+d3*d3;
    #pragma unroll
    for (int o=16;o;o>>=1) v += __shfl_xor(v,o,64);
    float rstd = rsqrtf(v*(1.f/128.f)+1e-8f);
    float y0=d0*rstd*g[l]+b[l];
    float y1=d1*rstd*g[l+32]+b[l+32];
    float y2=d2*rstd*g[l+64]+b[l+64];
    float y3=d3*rstd*g[l+96]+b[l+96];
    float* o_ = sOut + r*128;
    o_[l]=y0; o_[l+32]=y1; o_[l+64]=y2; o_[l+96]=y3;
    if (qin_out){
        float* q = qin_out + (size_t)(r0+r)*128;
        q[l]=y0; q[l+32]=y1; q[l+64]=y2; q[l+96]=y3;
    }
}

// 2-row x 2-col register tile GEMM over K=128 from LDS. A-reads are wave-broadcast.
__device__ __forceinline__ void gemm2x2(const float* A, const unsigned short* sW,
        int ra, int rb, int c0, float* acc){
    float a00=0,a01=0,a10=0,a11=0;
    const float* Ar = A + ra*128;
    const float* Br = A + rb*128;
    #pragma unroll 8
    for (int k=0;k<128;k++){
        ushort2 wp = *(const ushort2*)(sW + k*128 + c0);
        float w0=us2f(wp.x), w1=us2f(wp.y);
        float x0=Ar[k], x1=Br[k];
        a00=fmaf(x0,w0,a00); a01=fmaf(x0,w1,a01);
        a10=fmaf(x1,w0,a10); a11=fmaf(x1,w1,a11);
    }
    acc[0]=a00; acc[1]=a01; acc[2]=a10; acc[3]=a11;
}

// LN1 + Q/K/V gemms for 8 rows in sA. Caller must have sA finalized + barrier passed,
// and all prior sW/sAq readers done.
__device__ void qkv_compute(float* sA, float* sAq, unsigned short* sW,
        const unsigned short* __restrict__ Wqb, const unsigned short* __restrict__ Wkb,
        const unsigned short* __restrict__ Wvb,
        const float* __restrict__ bq, const float* __restrict__ bk, const float* __restrict__ bv,
        const float* __restrict__ ln1g, const float* __restrict__ ln1b,
        const float* __restrict__ posK, const float* __restrict__ posV,
        float* __restrict__ qin, bf16* __restrict__ Qo, bf16* __restrict__ Ko,
        bf16* __restrict__ Vo, int r0, int tid){
    ln_rows(sA, sAq, ln1g, ln1b, qin, r0, tid);
    stage_w(Wqb, sW, tid);
    __syncthreads();
    int cp = tid & 63, rp = tid >> 6;
    int c0 = 2*cp, ra = 2*rp, rb = ra+1;
    float acc[4];
    // Q = LN1(x) @ Wq + bq
    gemm2x2(sAq, sW, ra, rb, c0, acc);
    {
        float b0v = bq[c0], b1v = bq[c0+1];
        ushort2 s0; s0.x=f2us(acc[0]+b0v); s0.y=f2us(acc[1]+b1v);
        ushort2 s1; s1.x=f2us(acc[2]+b0v); s1.y=f2us(acc[3]+b1v);
        *(ushort2*)((unsigned short*)Qo + (size_t)(r0+ra)*128 + c0) = s0;
        *(ushort2*)((unsigned short*)Qo + (size_t)(r0+rb)*128 + c0) = s1;
    }
    __syncthreads();
    stage_w(Wkb, sW, tid);
    __syncthreads();
    // K' = x @ Wk + bk + posK[q]
    gemm2x2(sA, sW, ra, rb, c0, acc);
    {
        int qa = (r0+ra)&(L_-1), qb2 = (r0+rb)&(L_-1);
        float b0v = bk[c0], b1v = bk[c0+1];
        ushort2 s0; s0.x=f2us(acc[0]+b0v+posK[qa*128+c0]);  s0.y=f2us(acc[1]+b1v+posK[qa*128+c0+1]);
        ushort2 s1; s1.x=f2us(acc[2]+b0v+posK[qb2*128+c0]); s1.y=f2us(acc[3]+b1v+posK[qb2*128+c0+1]);
        *(ushort2*)((unsigned short*)Ko + (size_t)(r0+ra)*128 + c0) = s0;
        *(ushort2*)((unsigned short*)Ko + (size_t)(r0+rb)*128 + c0) = s1;
    }
    __syncthreads();
    stage_w(Wvb, sW, tid);
    __syncthreads();
    // V' = x @ Wv + bv + posV[q]
    gemm2x2(sA, sW, ra, rb, c0, acc);
    {
        int qa = (r0+ra)&(L_-1), qb2 = (r0+rb)&(L_-1);
        float b0v = bv[c0], b1v = bv[c0+1];
        ushort2 s0; s0.x=f2us(acc[0]+b0v+posV[qa*128+c0]);  s0.y=f2us(acc[1]+b1v+posV[qa*128+c0+1]);
        ushort2 s1; s1.x=f2us(acc[2]+b0v+posV[qb2*128+c0]); s1.y=f2us(acc[3]+b1v+posV[qb2*128+c0+1]);
        *(ushort2*)((unsigned short*)Vo + (size_t)(r0+ra)*128 + c0) = s0;
        *(ushort2*)((unsigned short*)Vo + (size_t)(r0+rb)*128 + c0) = s1;
    }
}

__global__ __launch_bounds__(256) void k_qkv(const float* __restrict__ seqs,
        const unsigned short* __restrict__ Wqb, const unsigned short* __restrict__ Wkb,
        const unsigned short* __restrict__ Wvb,
        const float* bq, const float* bk, const float* bv,
        const float* ln1g, const float* ln1b,
        const float* posK, const float* posV,
        float* qin, bf16* Qo, bf16* Ko, bf16* Vo){
    __shared__ unsigned short sW[16384];
    __shared__ float sA[1024], sAq[1024];
    int tid = threadIdx.x; int r0 = blockIdx.x*8;
    #pragma unroll
    for (int i=0;i<4;i++) sA[tid+i*256] = seqs[(size_t)r0*128 + tid + i*256];
    __syncthreads();
    qkv_compute(sA,sAq,sW,Wqb,Wkb,Wvb,bq,bk,bv,ln1g,ln1b,posK,posV,qin,Qo,Ko,Vo,r0,tid);
}

// FFN(layer i) fused with LN1+QKV(layer i+1); seqs never leaves LDS.
__global__ __launch_bounds__(256) void k_ffnqkv(const float* __restrict__ x,
        const unsigned short* __restrict__ W1b, const unsigned short* __restrict__ W2b,
        const float* b1, const float* b2, const int* __restrict__ maskids,
        const unsigned short* __restrict__ Wqb, const unsigned short* __restrict__ Wkb,
        const unsigned short* __restrict__ Wvb,
        const float* bq, const float* bk, const float* bv,
        const float* ln1g, const float* ln1b,
        const float* posK, const float* posV,
        float* qin, bf16* Qo, bf16* Ko, bf16* Vo){
    __shared__ unsigned short sW[16384];
    __shared__ float sA[1024], sH[1024];
    int tid=threadIdx.x; int r0=blockIdx.x*8;
    #pragma unroll
    for (int i=0;i<4;i++) sA[tid+i*256] = x[(size_t)r0*128 + tid + i*256];
    stage_w(W1b, sW, tid);
    __syncthreads();
    int cp=tid&63, rp=tid>>6, c0=2*cp, ra=2*rp, rb=ra+1;
    float acc[4];
    gemm2x2(sA, sW, ra, rb, c0, acc);
    {
        float b0v=b1[c0], b1v=b1[c0+1];
        sH[ra*128+c0]   = fmaxf(acc[0]+b0v,0.f);
        sH[ra*128+c0+1] = fmaxf(acc[1]+b1v,0.f);
        sH[rb*128+c0]   = fmaxf(acc[2]+b0v,0.f);
        sH[rb*128+c0+1] = fmaxf(acc[3]+b1v,0.f);
    }
    __syncthreads();
    stage_w(W2b, sW, tid);
    __syncthreads();
    gemm2x2(sH, sW, ra, rb, c0, acc);
    float f00,f01,f10,f11;
    {
        float b0v=b2[c0], b1v=b2[c0+1];
        bool m0 = maskids[r0+ra]==0, m1 = maskids[r0+rb]==0;
        f00 = m0?0.f:(acc[0]+b0v+sA[ra*128+c0]);
        f01 = m0?0.f:(acc[1]+b1v+sA[ra*128+c0+1]);
        f10 = m1?0.f:(acc[2]+b0v+sA[rb*128+c0]);
        f11 = m1?0.f:(acc[3]+b1v+sA[rb*128+c0+1]);
    }
    __syncthreads();                   // all reads of sA/sH/sW done
    sA[ra*128+c0]=f00; sA[ra*128+c0+1]=f01; sA[rb*128+c0]=f10; sA[rb*128+c0+1]=f11;
    __syncthreads();
    qkv_compute(sA,sH,sW,Wqb,Wkb,Wvb,bq,bk,bv,ln1g,ln1b,posK,posV,qin,Qo,Ko,Vo,r0,tid);
}

// final FFN + final LN + pos/neg logits (row-local)
__global__ __launch_bounds__(256) void k_ffnlogits(const float* __restrict__ x,
        const unsigned short* __restrict__ W1b, const unsigned short* __restrict__ W2b,
        const float* b1, const float* b2, const int* __restrict__ maskids,
        const float* __restrict__ lnfg, const float* __restrict__ lnfb,
        const int* __restrict__ pos_seqs, const int* __restrict__ neg_seqs,
        const float* __restrict__ item_emb, float* __restrict__ outp){
    __shared__ unsigned short sW[16384];
    __shared__ float sA[1024], sH[1024];
    int tid=threadIdx.x; int r0=blockIdx.x*8;
    #pragma unroll
    for (int i=0;i<4;i++) sA[tid+i*256] = x[(size_t)r0*128 + tid + i*256];
    stage_w(W1b, sW, tid);
    __syncthreads();
    int cp=tid&63, rp=tid>>6, c0=2*cp, ra=2*rp, rb=ra+1;
    float acc[4];
    gemm2x2(sA, sW, ra, rb, c0, acc);
    {
        float b0v=b1[c0], b1v=b1[c0+1];
        sH[ra*128+c0]   = fmaxf(acc[0]+b0v,0.f);
        sH[ra*128+c0+1] = fmaxf(acc[1]+b1v,0.f);
        sH[rb*128+c0]   = fmaxf(acc[2]+b0v,0.f);
        sH[rb*128+c0+1] = fmaxf(acc[3]+b1v,0.f);
    }
    __syncthreads();
    stage_w(W2b, sW, tid);
    __syncthreads();
    gemm2x2(sH, sW, ra, rb, c0, acc);
    float f00,f01,f10,f11;
    {
        float b0v=b2[c0], b1v=b2[c0+1];
        bool m0 = maskids[r0+ra]==0, m1 = maskids[r0+rb]==0;
        f00 = m0?0.f:(acc[0]+b0v+sA[ra*128+c0]);
        f01 = m0?0.f:(acc[1]+b1v+sA[ra*128+c0+1]);
        f10 = m1?0.f:(acc[2]+b0v+sA[rb*128+c0]);
        f11 = m1?0.f:(acc[3]+b1v+sA[rb*128+c0+1]);
    }
    __syncthreads();
    sA[ra*128+c0]=f00; sA[ra*128+c0+1]=f01; sA[rb*128+c0]=f10; sA[rb*128+c0+1]=f11;
    __syncthreads();
    ln_rows(sA, sH, lnfg, lnfb, nullptr, r0, tid);   // feats -> sH
    __syncthreads();
    int w = tid>>6, lane = tid&63;
    #pragma unroll
    for (int j=0;j<4;j++){
        int o = w*4 + j;                 // 0..15 = 8 rows x {pos,neg}
        int row = o>>1; int neg = o&1;
        int rg = r0 + row;
        int id = neg ? neg_seqs[rg] : pos_seqs[rg];
        const float* e = item_emb + (size_t)id*128;
        const float* fr = sH + row*128;
        float s = fr[lane]*e[lane] + fr[lane+64]*e[lane+64];
        #pragma unroll
        for (int oo=32;oo;oo>>=1) s += __shfl_xor(s,oo,64);
        if (lane==0) outp[(neg?ROWS:0) + rg] = s;
    }
}

// attention: one block per (b, q-pair {p, 255-p}) -> perfectly balanced work.
// K'/V' include posK/posV. LN2 fused into epilogue.
__global__ __launch_bounds__(256) void k_attn(
        const bf16* __restrict__ Q, const bf16* __restrict__ Kb,
        const bf16* __restrict__ Vb, const float* __restrict__ qin,
        const int* __restrict__ log_seqs, const int* __restrict__ tmat,
        const float* __restrict__ timeK, const float* __restrict__ timeV,
        const float* __restrict__ ln2g, const float* __restrict__ ln2b,
        float* __restrict__ outseq){
    __shared__ __align__(16) float sQ[2][D_];
    __shared__ float sS[2][H_][L_];
    __shared__ int   sTM[2][L_];
    __shared__ float sPr[2][8][D_];
    __shared__ float sRed[2][2], sRed2[2][2];
    int tid = threadIdx.x;
    int b = blockIdx.x >> 7, p = blockIdx.x & 127;
    int q1 = p, q2 = L_-1-p;
    int b0 = b*L_;
    int r1 = b0+q1, r2 = b0+q2;
    bool pad1 = log_seqs[r1]==0, pad2 = log_seqs[r2]==0;
    if (tid < 128) sQ[0][tid] = b2f(Q[(size_t)r1*128+tid]);
    else           sQ[1][tid-128] = b2f(Q[(size_t)r2*128+(tid-128)]);
    int k = tid;
    int tmv1 = tmat[(size_t)r1*L_+k], tmv2 = tmat[(size_t)r2*L_+k];
    sTM[0][k]=tmv1; sTM[1][k]=tmv2;
    __syncthreads();

    // phase 1: scores; K row loaded once, reused for both queries
    {
        const uint4* K4 = (const uint4*)(Kb + (size_t)(b0+k)*128);
        const float scale = 0.17677669529663687f;   // 1/sqrt(32)
        #pragma unroll
        for (int i=0;i<2;i++){
            int qq = i? q2:q1; bool pad = i? pad2:pad1;
            int tm = i? tmv2:tmv1;
            bool act = (k<=qq) && !pad;
            float acc[4] = {0.f,0.f,0.f,0.f};
            if (act){
                const float4* T4 = (const float4*)(timeK + (size_t)tm*128);
                const float4* Q4 = (const float4*)sQ[i];
                #pragma unroll
                for (int c=0;c<16;c++){
                    uint4 kv = K4[c];
                    float4 ta = T4[2*c], tb = T4[2*c+1];
                    float4 qa = Q4[2*c], qb = Q4[2*c+1];
                    const unsigned short* ku = (const unsigned short*)&kv;
                    acc[c>>2] += qa.x*(us2f(ku[0])+ta.x)
                               + qa.y*(us2f(ku[1])+ta.y)
                               + qa.z*(us2f(ku[2])+ta.z)
                               + qa.w*(us2f(ku[3])+ta.w)
                               + qb.x*(us2f(ku[4])+tb.x)
                               + qb.y*(us2f(ku[5])+tb.y)
                               + qb.z*(us2f(ku[6])+tb.z)
                               + qb.w*(us2f(ku[7])+tb.w);
                }
            }
            #pragma unroll
            for (int h=0;h<H_;h++) sS[i][h][k] = act ? acc[h]*scale : NEGV;
        }
    }
    __syncthreads();

    // phase 2: softmax; wave h handles head h for both queries
    {
        int h = tid>>6, lane = tid&63;
        #pragma unroll
        for (int i=0;i<2;i++){
            float v0=sS[i][h][lane], v1=sS[i][h][lane+64],
                  v2=sS[i][h][lane+128], v3=sS[i][h][lane+192];
            float m = fmaxf(fmaxf(v0,v1),fmaxf(v2,v3));
            #pragma unroll
            for (int o=32;o;o>>=1) m = fmaxf(m,__shfl_xor(m,o,64));
            float e0=__expf(v0-m), e1=__expf(v1-m), e2=__expf(v2-m), e3=__expf(v3-m);
            float ss=e0+e1+e2+e3;
            #pragma unroll
            for (int o=32;o;o>>=1) ss += __shfl_xor(ss,o,64);
            float inv = 1.f/ss;
            sS[i][h][lane]=e0*inv;     sS[i][h][lane+64]=e1*inv;
            sS[i][h][lane+128]=e2*inv; sS[i][h][lane+192]=e3*inv;
        }
    }
    __syncthreads();

    // phase 3: A @ (V' + timeV); causal clamp per query
    {
        int dq = tid&31, slice = tid>>5, h = dq>>3;
        #pragma unroll
        for (int i=0;i<2;i++){
            int qq = i? q2:q1; bool pad = i? pad2:pad1;
            int kend = pad? L_ : qq+1;
            int k0 = slice*32;
            int kmax = kend - k0; kmax = kmax<0?0:(kmax>32?32:kmax);
            float a0=0,a1=0,a2=0,a3=0;
            for (int kk=0;kk<kmax;kk++){
                int kx = k0+kk;
                float a = sS[i][h][kx];
                int tmk = sTM[i][kx];
                ushort4 v4 = ((const ushort4*)(Vb + (size_t)(b0+kx)*128))[dq];
                float4 t4 = ((const float4*)(timeV + (size_t)tmk*128))[dq];
                a0 = fmaf(a, us2f(v4.x)+t4.x, a0);
                a1 = fmaf(a, us2f(v4.y)+t4.y, a1);
                a2 = fmaf(a, us2f(v4.z)+t4.z, a2);
                a3 = fmaf(a, us2f(v4.w)+t4.w, a3);
            }
            ((float4*)sPr[i][slice])[dq] = make_float4(a0,a1,a2,a3);
        }
    }
    __syncthreads();

    // epilogue: out + q_in residual, then LN2 (row split across 2 waves)
    {
        int i = tid>>7, l = tid&127;
        int rr = i? r2:r1;
        float v = qin[(size_t)rr*128 + l];
        #pragma unroll
        for (int sl=0;sl<8;sl++) v += sPr[i][sl][l];
        float s = v;
        #pragma unroll
        for (int o=32;o;o>>=1) s += __shfl_xor(s,o,64);
        if ((tid&63)==0) sRed[i][(tid>>6)&1] = s;
        __syncthreads();
        float m = (sRed[i][0]+sRed[i][1])*(1.f/128.f);
        float d = v-m;
        float vv = d*d;
        #pragma unroll
        for (int o=32;o;o>>=1) vv += __shfl_xor(vv,o,64);
        if ((tid&63)==0) sRed2[i][(tid>>6)&1] = vv;
        __syncthreads();
        float rstd = rsqrtf((sRed2[i][0]+sRed2[i][1])*(1.f/128.f)+1e-8f);
        outseq[(size_t)rr*128+l] = d*rstd*ln2g[l]+ln2b[l];
    }
}

extern "C" void kernel_launch(void* const* d_in, const int* in_sizes, int n_in,
                              void* d_out, int out_size, void* d_ws, size_t ws_size,
                              hipStream_t stream) {
    const int* log_seqs = (const int*)d_in[1];
    const int* tmat     = (const int*)d_in[2];
    const int* pos_seqs = (const int*)d_in[3];
    const int* neg_seqs = (const int*)d_in[4];
    const float* item_emb = (const float*)d_in[5];
    const float* posK  = (const float*)d_in[6];
    const float* posV  = (const float*)d_in[7];
    const float* timeK = (const float*)d_in[8];
    const float* timeV = (const float*)d_in[9];
    const float* ln1_g = (const float*)d_in[10];
    const float* ln1_b = (const float*)d_in[11];
    const float* Wq = (const float*)d_in[12];
    const float* bqv = (const float*)d_in[13];
    const float* Wk = (const float*)d_in[14];
    const float* bk = (const float*)d_in[15];
    const float* Wv = (const float*)d_in[16];
    const float* bv = (const float*)d_in[17];
    const float* ln2_g = (const float*)d_in[18];
    const float* ln2_b = (const float*)d_in[19];
    const float* W1 = (const float*)d_in[20];
    const float* b1 = (const float*)d_in[21];
    const float* W2 = (const float*)d_in[22];
    const float* b2 = (const float*)d_in[23];
    const float* lnf_g = (const float*)d_in[24];
    const float* lnf_b = (const float*)d_in[25];

    // ws: [0,1MB) seqs fp32 | [1,2MB) qin fp32 | [2,2.5) Q bf16 | [2.5,3) K bf16
    //     [3,3.5) V bf16 | [3.5MB, +320KB) wsW bf16 (10 x 128x128)
    const int NE = ROWS * D_;       // 262144
    char* wsb = (char*)d_ws;
    float* s_seqs = (float*)(wsb + 0);
    float* s_qin  = (float*)(wsb + (size_t)NE * 4);
    bf16*  s_Q    = (bf16*) (wsb + (size_t)NE * 8);
    bf16*  s_K    = (bf16*) (wsb + (size_t)NE * 8 + (size_t)NE * 2);
    bf16*  s_V    = (bf16*) (wsb + (size_t)NE * 8 + (size_t)NE * 4);
    unsigned short* wsW = (unsigned short*)(wsb + (size_t)NE * 8 + (size_t)NE * 6);

    const int DD = D_*D_;   // 16384
    WPtrs wp;
    wp.p[0]=Wq;      wp.p[1]=Wk;      wp.p[2]=Wv;      wp.p[3]=W1;      wp.p[4]=W2;
    wp.p[5]=Wq+DD;   wp.p[6]=Wk+DD;   wp.p[7]=Wv+DD;   wp.p[8]=W1+DD;   wp.p[9]=W2+DD;

    k_prep<<<416, 256, 0, stream>>>(item_emb, log_seqs, s_seqs, wp, wsW);

    // layer 0
    k_qkv<<<256, 256, 0, stream>>>(s_seqs, wsW+0*DD, wsW+1*DD, wsW+2*DD,
            bqv, bk, bv, ln1_g, ln1_b, posK, posV, s_qin, s_Q, s_K, s_V);
    k_attn<<<1024, 256, 0, stream>>>(s_Q, s_K, s_V, s_qin, log_seqs, tmat,
            timeK, timeV, ln2_g, ln2_b, s_seqs);
    // ffn(layer0) + qkv(layer1)
    k_ffnqkv<<<256, 256, 0, stream>>>(s_seqs, wsW+3*DD, wsW+4*DD, b1, b2, log_seqs,
            wsW+5*DD, wsW+6*DD, wsW+7*DD, bqv+D_, bk+D_, bv+D_,
            ln1_g+D_, ln1_b+D_, posK, posV, s_qin, s_Q, s_K, s_V);
    k_attn<<<1024, 256, 0, stream>>>(s_Q, s_K, s_V, s_qin, log_seqs, tmat,
            timeK, timeV, ln2_g+D_, ln2_b+D_, s_seqs);
    // ffn(layer1) + lnf + logits
    k_ffnlogits<<<256, 256, 0, stream>>>(s_seqs, wsW+8*DD, wsW+9*DD, b1+D_, b2+D_,
            log_seqs, lnf_g, lnf_b, pos_seqs, neg_seqs, item_emb, (float*)d_out);
}

// Round 6
// 218.923 us; speedup vs baseline: 2.3306x; 1.1088x over previous
//
#include <hip/hip_runtime.h>
#include <hip/hip_bf16.h>

#define B_ 8
#define L_ 256
#define D_ 128
#define H_ 4
#define NB_ 2
#define ROWS (B_*L_)            // 2048
#define NEGV (-4294967295.0f)   // -(2^32)+1 as float

typedef __hip_bfloat16 bf16;

__device__ __forceinline__ float us2f(unsigned short u){ return __uint_as_float(((unsigned)u)<<16); }
__device__ __forceinline__ unsigned short f2us(float f){ bf16 h=__float2bfloat16(f); return *(unsigned short*)&h; }
__device__ __forceinline__ float b2f(bf16 x){ return __bfloat162float(x); }

struct WPtrs { const float* p[10]; };   // Wq0,Wk0,Wv0,W1_0,W2_0, Wq1,Wk1,Wv1,W1_1,W2_1

// fused one-time prep:
//   blocks [0,256)   : seqs = item_emb[log_seqs]*sqrt(D), pad-zeroed
//   blocks [256,416) : 10 weight matrices fp32 -> bf16 into wsW
//   blocks [416,482) : timeK/timeV fp32 -> bf16 tables (257x128 each)
__global__ __launch_bounds__(256) void k_prep(const float* __restrict__ item_emb,
        const int* __restrict__ log_seqs, float* __restrict__ seqs,
        WPtrs wp, unsigned short* __restrict__ wsW,
        const float* __restrict__ timeK, const float* __restrict__ timeV,
        unsigned short* __restrict__ tmK, unsigned short* __restrict__ tmV) {
    int tid = threadIdx.x, bid = blockIdx.x;
    if (bid < 256) {
        int gi = bid*256 + tid;          // float4 index, 65536 total
        int r = gi >> 5, c4 = gi & 31;
        int id = log_seqs[r];
        float4 v = ((const float4*)item_emb)[id*32 + c4];
        float sc = (id==0) ? 0.0f : 11.3137085f;   // sqrt(128)
        v.x*=sc; v.y*=sc; v.z*=sc; v.w*=sc;
        ((float4*)seqs)[gi] = v;
    } else if (bid < 416) {
        int m = (bid-256) >> 4, ch = (bid-256) & 15;
        float4 v = ((const float4*)wp.p[m])[ch*256 + tid];
        ushort4 o; o.x=f2us(v.x); o.y=f2us(v.y); o.z=f2us(v.z); o.w=f2us(v.w);
        ((ushort4*)(wsW + (size_t)m*16384))[ch*256 + tid] = o;
    } else {
        int gi = (bid-416)*256 + tid;    // float4 idx over 2x 8224
        if (gi < 8224) {
            float4 v = ((const float4*)timeK)[gi];
            ushort4 o; o.x=f2us(v.x); o.y=f2us(v.y); o.z=f2us(v.z); o.w=f2us(v.w);
            ((ushort4*)tmK)[gi] = o;
        } else if (gi < 16448) {
            int gj = gi - 8224;
            float4 v = ((const float4*)timeV)[gj];
            ushort4 o; o.x=f2us(v.x); o.y=f2us(v.y); o.z=f2us(v.z); o.w=f2us(v.w);
            ((ushort4*)tmV)[gj] = o;
        }
    }
}

// stage one 128x128 bf16 matrix (32KB) global -> LDS
__device__ __forceinline__ void stage_w(const unsigned short* __restrict__ Wg,
                                        unsigned short* sW, int tid){
    const uint4* src = (const uint4*)Wg;
    uint4* dst = (uint4*)sW;
    #pragma unroll
    for (int j=0;j<8;j++) dst[j*256+tid] = src[j*256+tid];
}

// LayerNorm of 8 LDS rows; thread t: row t>>5, 4 elems strided 32.
__device__ __forceinline__ void ln_rows(const float* sA, float* sOut,
        const float* __restrict__ g, const float* __restrict__ b,
        float* qin_out, int r0, int tid){
    int r = tid>>5, l = tid&31;
    const float* x = sA + r*128;
    float x0=x[l], x1=x[l+32], x2=x[l+64], x3=x[l+96];
    float s = x0+x1+x2+x3;
    #pragma unroll
    for (int o=16;o;o>>=1) s += __shfl_xor(s,o,64);
    float m = s*(1.f/128.f);
    float d0=x0-m,d1=x1-m,d2=x2-m,d3=x3-m;
    float v = d0*d0+d1*d1+d2*d2+d3*d3;
    #pragma unroll
    for (int o=16;o;o>>=1) v += __shfl_xor(v,o,64);
    float rstd = rsqrtf(v*(1.f/128.f)+1e-8f);
    float y0=d0*rstd*g[l]+b[l];
    float y1=d1*rstd*g[l+32]+b[l+32];
    float y2=d2*rstd*g[l+64]+b[l+64];
    float y3=d3*rstd*g[l+96]+b[l+96];
    float* o_ = sOut + r*128;
    o_[l]=y0; o_[l+32]=y1; o_[l+64]=y2; o_[l+96]=y3;
    if (qin_out){
        float* q = qin_out + (size_t)(r0+r)*128;
        q[l]=y0; q[l+32]=y1; q[l+64]=y2; q[l+96]=y3;
    }
}

// 2-row x 2-col register tile over K=128 from LDS (A-reads wave-broadcast)
__device__ __forceinline__ void gemm2x2(const float* A, const unsigned short* sW,
        int ra, int rb, int c0, float* acc){
    float a00=0,a01=0,a10=0,a11=0;
    const float* Ar = A + ra*128;
    const float* Br = A + rb*128;
    #pragma unroll 8
    for (int k=0;k<128;k++){
        ushort2 wp = *(const ushort2*)(sW + k*128 + c0);
        float w0=us2f(wp.x), w1=us2f(wp.y);
        float x0=Ar[k], x1=Br[k];
        a00=fmaf(x0,w0,a00); a01=fmaf(x0,w1,a01);
        a10=fmaf(x1,w0,a10); a11=fmaf(x1,w1,a11);
    }
    acc[0]=a00; acc[1]=a01; acc[2]=a10; acc[3]=a11;
}

// 1-row x 2-col tile (for 4-row FFN blocks)
__device__ __forceinline__ void gemm1x2(const float* Ar, const unsigned short* sW,
        int c0, float& o0, float& o1){
    float a0=0,a1=0;
    #pragma unroll 8
    for (int k=0;k<128;k++){
        ushort2 wp = *(const ushort2*)(sW + k*128 + c0);
        float x = Ar[k];
        a0 = fmaf(x, us2f(wp.x), a0);
        a1 = fmaf(x, us2f(wp.y), a1);
    }
    o0=a0; o1=a1;
}

// QKV: grid 768 = {Q,K,V} x 256 row-groups of 8. Q-blocks compute LN1 + write qin.
__global__ __launch_bounds__(256) void k_qkv(const float* __restrict__ seqs,
        const unsigned short* __restrict__ Wqb, const unsigned short* __restrict__ Wkb,
        const unsigned short* __restrict__ Wvb,
        const float* __restrict__ bq, const float* __restrict__ bk, const float* __restrict__ bv,
        const float* __restrict__ ln1g, const float* __restrict__ ln1b,
        const float* __restrict__ posK, const float* __restrict__ posV,
        float* __restrict__ qin, bf16* __restrict__ Qo, bf16* __restrict__ Ko,
        bf16* __restrict__ Vo){
    __shared__ unsigned short sW[16384];
    __shared__ float sA[1024], sAq[1024];
    int tid = threadIdx.x;
    int m = blockIdx.x >> 8;            // 0=Q, 1=K, 2=V
    int rg = blockIdx.x & 255;
    int r0 = rg*8;
    ((float4*)sA)[tid] = ((const float4*)(seqs + (size_t)r0*128))[tid];
    const unsigned short* Wg = (m==0)?Wqb:(m==1)?Wkb:Wvb;
    stage_w(Wg, sW, tid);
    __syncthreads();
    const float* src = sA;
    if (m==0){
        ln_rows(sA, sAq, ln1g, ln1b, qin, r0, tid);
        src = sAq;
        __syncthreads();
    }
    int cp = tid & 63, rp = tid >> 6;
    int c0 = 2*cp, ra = 2*rp, rb = ra+1;
    float acc[4];
    gemm2x2(src, sW, ra, rb, c0, acc);
    if (m==0){
        float b0v = bq[c0], b1v = bq[c0+1];
        ushort2 s0; s0.x=f2us(acc[0]+b0v); s0.y=f2us(acc[1]+b1v);
        ushort2 s1; s1.x=f2us(acc[2]+b0v); s1.y=f2us(acc[3]+b1v);
        *(ushort2*)((unsigned short*)Qo + (size_t)(r0+ra)*128 + c0) = s0;
        *(ushort2*)((unsigned short*)Qo + (size_t)(r0+rb)*128 + c0) = s1;
    } else {
        const float* bb = (m==1)?bk:bv;
        const float* pp = (m==1)?posK:posV;
        bf16* Oo = (m==1)?Ko:Vo;
        int qa = (r0+ra)&(L_-1), qb2 = (r0+rb)&(L_-1);
        float b0v = bb[c0], b1v = bb[c0+1];
        ushort2 s0; s0.x=f2us(acc[0]+b0v+pp[qa*128+c0]);  s0.y=f2us(acc[1]+b1v+pp[qa*128+c0+1]);
        ushort2 s1; s1.x=f2us(acc[2]+b0v+pp[qb2*128+c0]); s1.y=f2us(acc[3]+b1v+pp[qb2*128+c0+1]);
        *(ushort2*)((unsigned short*)Oo + (size_t)(r0+ra)*128 + c0) = s0;
        *(ushort2*)((unsigned short*)Oo + (size_t)(r0+rb)*128 + c0) = s1;
    }
}

// FFN: grid 512 x 4 rows. x (=LN2 output) in, x + mask-residual out (in place).
__global__ __launch_bounds__(256) void k_ffn(float* __restrict__ x,
        const unsigned short* __restrict__ W1b, const unsigned short* __restrict__ W2b,
        const float* __restrict__ b1, const float* __restrict__ b2,
        const int* __restrict__ maskids){
    __shared__ unsigned short sW[16384];
    __shared__ float sA[512], sH[512];
    int tid=threadIdx.x; int r0=blockIdx.x*4;
    sA[tid]     = x[(size_t)r0*128 + tid];
    sA[tid+256] = x[(size_t)r0*128 + tid + 256];
    stage_w(W1b, sW, tid);
    __syncthreads();
    int cp=tid&63, rp=tid>>6, c0=2*cp;
    float h0,h1;
    gemm1x2(sA + rp*128, sW, c0, h0, h1);
    sH[rp*128+c0]   = fmaxf(h0+b1[c0],0.f);
    sH[rp*128+c0+1] = fmaxf(h1+b1[c0+1],0.f);
    __syncthreads();
    stage_w(W2b, sW, tid);
    __syncthreads();
    float f0,f1;
    gemm1x2(sH + rp*128, sW, c0, f0, f1);
    bool msk = maskids[r0+rp]==0;
    f0 = msk?0.f:(f0+b2[c0]  +sA[rp*128+c0]);
    f1 = msk?0.f:(f1+b2[c0+1]+sA[rp*128+c0+1]);
    x[(size_t)(r0+rp)*128 + c0]   = f0;
    x[(size_t)(r0+rp)*128 + c0+1] = f1;
}

// final LN + pos/neg logits: grid 256 x 8 rows
__global__ __launch_bounds__(256) void k_lnlogits(const float* __restrict__ x,
        const float* __restrict__ lnfg, const float* __restrict__ lnfb,
        const int* __restrict__ pos_seqs, const int* __restrict__ neg_seqs,
        const float* __restrict__ item_emb, float* __restrict__ outp){
    __shared__ float sA[1024], sH[1024];
    int tid=threadIdx.x; int r0=blockIdx.x*8;
    ((float4*)sA)[tid] = ((const float4*)(x + (size_t)r0*128))[tid];
    __syncthreads();
    ln_rows(sA, sH, lnfg, lnfb, nullptr, r0, tid);
    __syncthreads();
    int w = tid>>6, lane = tid&63;
    #pragma unroll
    for (int j=0;j<4;j++){
        int o = w*4 + j;                 // 16 = 8 rows x {pos,neg}
        int row = o>>1; int neg = o&1;
        int rg = r0 + row;
        int id = neg ? neg_seqs[rg] : pos_seqs[rg];
        const float* e = item_emb + (size_t)id*128;
        const float* fr = sH + row*128;
        float s = fr[lane]*e[lane] + fr[lane+64]*e[lane+64];
        #pragma unroll
        for (int oo=32;oo;oo>>=1) s += __shfl_xor(s,oo,64);
        if (lane==0) outp[(neg?ROWS:0) + rg] = s;
    }
}

// attention: one block per (b, q-pair {p,255-p}); K'/V' include posK/posV;
// bf16 time tables; LN2 fused in epilogue. scale folded into sQ.
__global__ __launch_bounds__(256) void k_attn(
        const bf16* __restrict__ Q, const bf16* __restrict__ Kb,
        const bf16* __restrict__ Vb, const float* __restrict__ qin,
        const int* __restrict__ log_seqs, const int* __restrict__ tmat,
        const unsigned short* __restrict__ tmK, const unsigned short* __restrict__ tmV,
        const float* __restrict__ ln2g, const float* __restrict__ ln2b,
        float* __restrict__ outseq){
    __shared__ __align__(16) float sQ[2][D_];
    __shared__ float sS[2][H_][L_];
    __shared__ int   sTM[2][L_];
    __shared__ float sPr[2][8][D_];
    __shared__ float sRed[2][2], sRed2[2][2];
    int tid = threadIdx.x;
    int b = blockIdx.x >> 7, p = blockIdx.x & 127;
    int q1 = p, q2 = L_-1-p;
    int b0 = b*L_;
    int r1 = b0+q1, r2 = b0+q2;
    bool pad1 = log_seqs[r1]==0, pad2 = log_seqs[r2]==0;
    const float scale = 0.17677669529663687f;   // 1/sqrt(32)
    if (tid < 128) sQ[0][tid] = b2f(Q[(size_t)r1*128+tid])*scale;
    else           sQ[1][tid-128] = b2f(Q[(size_t)r2*128+(tid-128)])*scale;
    int k = tid;
    int tmv1 = tmat[(size_t)r1*L_+k], tmv2 = tmat[(size_t)r2*L_+k];
    sTM[0][k]=tmv1; sTM[1][k]=tmv2;
    __syncthreads();

    // phase 1: scores; K row loaded per query, time row = 16 uint4 (bf16)
    {
        const uint4* K4 = (const uint4*)(Kb + (size_t)(b0+k)*128);
        #pragma unroll
        for (int i=0;i<2;i++){
            int qq = i? q2:q1; bool pad = i? pad2:pad1;
            int tm = i? tmv2:tmv1;
            bool act = (k<=qq) && !pad;
            float acc[4] = {0.f,0.f,0.f,0.f};
            if (act){
                const uint4* T4 = (const uint4*)(tmK + (size_t)tm*128);
                const float4* Q4 = (const float4*)sQ[i];
                #pragma unroll
                for (int c=0;c<16;c++){
                    uint4 kv = K4[c];
                    uint4 tv = T4[c];
                    float4 qa = Q4[2*c], qb = Q4[2*c+1];
                    const unsigned short* ku = (const unsigned short*)&kv;
                    const unsigned short* tu = (const unsigned short*)&tv;
                    acc[c>>2] += qa.x*(us2f(ku[0])+us2f(tu[0]))
                               + qa.y*(us2f(ku[1])+us2f(tu[1]))
                               + qa.z*(us2f(ku[2])+us2f(tu[2]))
                               + qa.w*(us2f(ku[3])+us2f(tu[3]))
                               + qb.x*(us2f(ku[4])+us2f(tu[4]))
                               + qb.y*(us2f(ku[5])+us2f(tu[5]))
                               + qb.z*(us2f(ku[6])+us2f(tu[6]))
                               + qb.w*(us2f(ku[7])+us2f(tu[7]));
                }
            }
            #pragma unroll
            for (int h=0;h<H_;h++) sS[i][h][k] = act ? acc[h] : NEGV;
        }
    }
    __syncthreads();

    // phase 2: softmax; wave h -> head h, both queries
    {
        int h = tid>>6, lane = tid&63;
        #pragma unroll
        for (int i=0;i<2;i++){
            float v0=sS[i][h][lane], v1=sS[i][h][lane+64],
                  v2=sS[i][h][lane+128], v3=sS[i][h][lane+192];
            float m = fmaxf(fmaxf(v0,v1),fmaxf(v2,v3));
            #pragma unroll
            for (int o=32;o;o>>=1) m = fmaxf(m,__shfl_xor(m,o,64));
            float e0=__expf(v0-m), e1=__expf(v1-m), e2=__expf(v2-m), e3=__expf(v3-m);
            float ss=e0+e1+e2+e3;
            #pragma unroll
            for (int o=32;o;o>>=1) ss += __shfl_xor(ss,o,64);
            float inv = 1.f/ss;
            sS[i][h][lane]=e0*inv;     sS[i][h][lane+64]=e1*inv;
            sS[i][h][lane+128]=e2*inv; sS[i][h][lane+192]=e3*inv;
        }
    }
    __syncthreads();

    // phase 3: A @ (V' + timeV); causal clamp per query; bf16 time table
    {
        int dq = tid&31, slice = tid>>5, h = dq>>3;
        #pragma unroll
        for (int i=0;i<2;i++){
            int qq = i? q2:q1; bool pad = i? pad2:pad1;
            int kend = pad? L_ : qq+1;
            int k0 = slice*32;
            int kmax = kend - k0; kmax = kmax<0?0:(kmax>32?32:kmax);
            float a0=0,a1=0,a2=0,a3=0;
            for (int kk=0;kk<kmax;kk++){
                int kx = k0+kk;
                float a = sS[i][h][kx];
                int tmk = sTM[i][kx];
                ushort4 v4 = ((const ushort4*)(Vb + (size_t)(b0+kx)*128))[dq];
                ushort4 t4 = ((const ushort4*)(tmV + (size_t)tmk*128))[dq];
                a0 = fmaf(a, us2f(v4.x)+us2f(t4.x), a0);
                a1 = fmaf(a, us2f(v4.y)+us2f(t4.y), a1);
                a2 = fmaf(a, us2f(v4.z)+us2f(t4.z), a2);
                a3 = fmaf(a, us2f(v4.w)+us2f(t4.w), a3);
            }
            ((float4*)sPr[i][slice])[dq] = make_float4(a0,a1,a2,a3);
        }
    }
    __syncthreads();

    // epilogue: +q_in residual, LN2 (each query row handled by 2 waves)
    {
        int i = tid>>7, l = tid&127;
        int rr = i? r2:r1;
        float v = qin[(size_t)rr*128 + l];
        #pragma unroll
        for (int sl=0;sl<8;sl++) v += sPr[i][sl][l];
        float s = v;
        #pragma unroll
        for (int o=32;o;o>>=1) s += __shfl_xor(s,o,64);
        if ((tid&63)==0) sRed[i][(tid>>6)&1] = s;
        __syncthreads();
        float m = (sRed[i][0]+sRed[i][1])*(1.f/128.f);
        float d = v-m;
        float vv = d*d;
        #pragma unroll
        for (int o=32;o;o>>=1) vv += __shfl_xor(vv,o,64);
        if ((tid&63)==0) sRed2[i][(tid>>6)&1] = vv;
        __syncthreads();
        float rstd = rsqrtf((sRed2[i][0]+sRed2[i][1])*(1.f/128.f)+1e-8f);
        outseq[(size_t)rr*128+l] = d*rstd*ln2g[l]+ln2b[l];
    }
}

extern "C" void kernel_launch(void* const* d_in, const int* in_sizes, int n_in,
                              void* d_out, int out_size, void* d_ws, size_t ws_size,
                              hipStream_t stream) {
    const int* log_seqs = (const int*)d_in[1];
    const int* tmat     = (const int*)d_in[2];
    const int* pos_seqs = (const int*)d_in[3];
    const int* neg_seqs = (const int*)d_in[4];
    const float* item_emb = (const float*)d_in[5];
    const float* posK  = (const float*)d_in[6];
    const float* posV  = (const float*)d_in[7];
    const float* timeK = (const float*)d_in[8];
    const float* timeV = (const float*)d_in[9];
    const float* ln1_g = (const float*)d_in[10];
    const float* ln1_b = (const float*)d_in[11];
    const float* Wq = (const float*)d_in[12];
    const float* bqv = (const float*)d_in[13];
    const float* Wk = (const float*)d_in[14];
    const float* bk = (const float*)d_in[15];
    const float* Wv = (const float*)d_in[16];
    const float* bv = (const float*)d_in[17];
    const float* ln2_g = (const float*)d_in[18];
    const float* ln2_b = (const float*)d_in[19];
    const float* W1 = (const float*)d_in[20];
    const float* b1 = (const float*)d_in[21];
    const float* W2 = (const float*)d_in[22];
    const float* b2 = (const float*)d_in[23];
    const float* lnf_g = (const float*)d_in[24];
    const float* lnf_b = (const float*)d_in[25];

    // ws: [0,1MB) seqs fp32 | [1,2MB) qin fp32 | [2,2.5) Q bf16 | [2.5,3) K bf16
    //     [3,3.5) V bf16 | +320KB wsW bf16 (10x128x128) | +64.25KB tmK | +64.25KB tmV
    const int NE = ROWS * D_;       // 262144
    char* wsb = (char*)d_ws;
    float* s_seqs = (float*)(wsb + 0);
    float* s_qin  = (float*)(wsb + (size_t)NE * 4);
    bf16*  s_Q    = (bf16*) (wsb + (size_t)NE * 8);
    bf16*  s_K    = (bf16*) (wsb + (size_t)NE * 8 + (size_t)NE * 2);
    bf16*  s_V    = (bf16*) (wsb + (size_t)NE * 8 + (size_t)NE * 4);
    unsigned short* wsW = (unsigned short*)(wsb + (size_t)NE * 14);
    unsigned short* tmK = (unsigned short*)(wsb + (size_t)NE * 14 + 327680);
    unsigned short* tmV = tmK + 32896;

    const int DD = D_*D_;   // 16384
    WPtrs wp;
    wp.p[0]=Wq;      wp.p[1]=Wk;      wp.p[2]=Wv;      wp.p[3]=W1;      wp.p[4]=W2;
    wp.p[5]=Wq+DD;   wp.p[6]=Wk+DD;   wp.p[7]=Wv+DD;   wp.p[8]=W1+DD;   wp.p[9]=W2+DD;

    k_prep<<<482, 256, 0, stream>>>(item_emb, log_seqs, s_seqs, wp, wsW,
                                    timeK, timeV, tmK, tmV);
    for (int i = 0; i < NB_; i++) {
        k_qkv<<<768, 256, 0, stream>>>(s_seqs, wsW+(5*i+0)*DD, wsW+(5*i+1)*DD, wsW+(5*i+2)*DD,
                bqv+i*D_, bk+i*D_, bv+i*D_, ln1_g+i*D_, ln1_b+i*D_, posK, posV,
                s_qin, s_Q, s_K, s_V);
        k_attn<<<1024, 256, 0, stream>>>(s_Q, s_K, s_V, s_qin, log_seqs, tmat,
                tmK, tmV, ln2_g+i*D_, ln2_b+i*D_, s_seqs);
        k_ffn<<<512, 256, 0, stream>>>(s_seqs, wsW+(5*i+3)*DD, wsW+(5*i+4)*DD,
                b1+i*D_, b2+i*D_, log_seqs);
    }
    k_lnlogits<<<256, 256, 0, stream>>>(s_seqs, lnf_g, lnf_b, pos_seqs, neg_seqs,
                                        item_emb, (float*)d_out);
}